// Round 4
// baseline (599.860 us; speedup 1.0000x reference)
//
#include <hip/hip_runtime.h>
#include <hip/hip_fp16.h>

typedef _Float16 h2 __attribute__((ext_vector_type(2)));

#define LOG2E 1.4426950408889634f
#define LN2   0.6931471805599453f

__device__ __forceinline__ float fast_exp2(float x) {
#if __has_builtin(__builtin_amdgcn_exp2f)
    return __builtin_amdgcn_exp2f(x);
#else
    return exp2f(x);
#endif
}

__device__ __forceinline__ float dot2(h2 a, h2 b, float c) {
#if __has_builtin(__builtin_amdgcn_fdot2)
    return __builtin_amdgcn_fdot2(a, b, c, false);
#else
    return (float)a.x * (float)b.x + (float)a.y * (float)b.y + c;
#endif
}

__device__ __forceinline__ h2 bch2(int x) { return __builtin_bit_cast(h2, x); }

// One block per batch element b. Thread j owns state-column j (E column in VGPRs).
// Exp-space linear recursion with FRESH per-step renorm (R2-proven numerics):
//   u = v * 2^(-k-2), k = ilogb(v_0) of the CURRENT step; C += k+2.
// Broadcast engine: one lane-spread ds_read_b64 per wave (whole u vector),
// then v_readlane -> SGPR -> v_dot2_f32_f16 against the register-resident E column.
__launch_bounds__(256, 1)
__global__ void crf_main(const float* __restrict__ emissions,
                         const int*   __restrict__ tags,
                         const float* __restrict__ mask,
                         const float* __restrict__ trans,
                         float*       __restrict__ ws) {
    const int T = 512, N = 256;
    const int b = blockIdx.x;
    const int j = threadIdx.x;
    const int lane = j & 63;

    __shared__ alignas(16) _Float16 u_lds[256];
    __shared__ float v0f;
    __shared__ float red[256];

    // ---- E column j -> registers as fp16 pairs, pinned in VGPRs ----
    const float* tcol = trans + j;            // column j: stride N, coalesced across lanes
    float cmax = -1e30f;
    #pragma unroll 8
    for (int i = 0; i < N; ++i) cmax = fmaxf(cmax, tcol[i * N]);
    const float cm2 = cmax * LOG2E;

    h2 Er[128];                               // E(2k,j), E(2k+1,j); E = 2^(t*log2e - cm2) in (0,1]
    #pragma unroll
    for (int k = 0; k < 128; ++k) {
        h2 e2;
        e2.x = (_Float16)fast_exp2(tcol[(2 * k)     * N] * LOG2E - cm2);
        e2.y = (_Float16)fast_exp2(tcol[(2 * k + 1) * N] * LOG2E - cm2);
        int ei = __builtin_bit_cast(int, e2);
        asm volatile("" : "+v"(ei));          // keep in arch VGPR (no AGPR/scratch)
        Er[k] = bch2(ei);
    }

    // ---- init: v = 2^(log2e * emit[b,0,j]) ----
    const float* em_base = emissions + ((size_t)b * T) * N + j;
    float v = fast_exp2(em_base[0] * LOG2E);
    float C = 0.f;
    float em_next  = em_base[N];              // emission t=1
    float em_next2 = em_base[2 * N];          // emission t=2 (2-step prefetch)

    if (j == 0) v0f = v;
    __syncthreads();
    {
        int   e = (__float_as_int(v0f) >> 23) & 0xff;   // biased exponent of v0
        float r = __int_as_float((252 - e) << 23);      // exact 2^(-k-2), k = e-127
        C += (float)(e - 125);                          // k + 2
        u_lds[j] = (_Float16)fminf(v * r, 60000.0f);    // clamp is inert insurance
    }
    __syncthreads();

    for (int t = 1; t < T; ++t) {
        // whole u vector, lane-spread: one ds_read_b64 per wave
        int2 ur = ((const int2*)u_lds)[lane];
        float em = em_next;
        em_next = em_next2;
        if (t + 2 < T) em_next2 = em_base[(size_t)(t + 2) * N];

        // matvec: pair p lives in lane p>>1 (x: even p, y: odd p)
        float a0 = 0.f, a1 = 0.f, a2 = 0.f, a3 = 0.f;
        float a4 = 0.f, a5 = 0.f, a6 = 0.f, a7 = 0.f;
        #pragma unroll
        for (int p = 0; p < 128; p += 8) {
            const int l = p >> 1;
            a0 = dot2(bch2(__builtin_amdgcn_readlane(ur.x, l)),     Er[p + 0], a0);
            a1 = dot2(bch2(__builtin_amdgcn_readlane(ur.y, l)),     Er[p + 1], a1);
            a2 = dot2(bch2(__builtin_amdgcn_readlane(ur.x, l + 1)), Er[p + 2], a2);
            a3 = dot2(bch2(__builtin_amdgcn_readlane(ur.y, l + 1)), Er[p + 3], a3);
            a4 = dot2(bch2(__builtin_amdgcn_readlane(ur.x, l + 2)), Er[p + 4], a4);
            a5 = dot2(bch2(__builtin_amdgcn_readlane(ur.y, l + 2)), Er[p + 5], a5);
            a6 = dot2(bch2(__builtin_amdgcn_readlane(ur.x, l + 3)), Er[p + 6], a6);
            a7 = dot2(bch2(__builtin_amdgcn_readlane(ur.y, l + 3)), Er[p + 7], a7);
        }
        float acc = (((a0 + a1) + (a2 + a3)) + ((a4 + a5) + (a6 + a7)));
        v = acc * fast_exp2(fmaf(em, LOG2E, cm2));      // fold emit + colmax back in

        if (j == 0) v0f = v;
        __syncthreads();                                 // bar A: v0 ready; u reads done
        if (t < T - 1) {
            int   e = (__float_as_int(v0f) >> 23) & 0xff;
            float r = __int_as_float((252 - e) << 23);   // 2^(-k-2), fresh k
            C += (float)(e - 125);
            u_lds[j] = (_Float16)fminf(v * r, 60000.0f);
        }
        __syncthreads();                                 // bar B: u ready
    }

    // ---- Z_b = ln2 * (C + log2(sum_j v_j)) ----
    red[j] = v;
    __syncthreads();
    #pragma unroll
    for (int s = 128; s > 0; s >>= 1) {
        if (j < s) red[j] += red[j + s];
        __syncthreads();
    }
    float Z = (C + log2f(red[0])) * LN2;
    __syncthreads();   // everyone done reading red[0] before reuse

    // ---- gold score (gather) ----
    float gp = 0.f;
    const int*   tg  = tags + (size_t)b * T;
    const float* mk  = mask + (size_t)b * T;
    const float* emb = emissions + ((size_t)b * T) * N;
    for (int t = 1 + j; t < T; t += 256) {
        int tt = tg[t], tp = tg[t - 1];
        gp += (emb[(size_t)t * N + tt] + trans[(size_t)tp * N + tt]) * mk[t];
    }
    if (j == 0) gp += emb[tg[0]];
    red[j] = gp;
    __syncthreads();
    #pragma unroll
    for (int s = 128; s > 0; s >>= 1) {
        if (j < s) red[j] += red[j + s];
        __syncthreads();
    }
    if (j == 0) ws[b] = Z - red[0];
}

// Deterministic mean over the 128 per-batch results.
__global__ void crf_finalize(const float* __restrict__ ws, float* __restrict__ out) {
    int l = threadIdx.x;                 // 64 threads, one wave
    float s = ws[l] + ws[l + 64];
    #pragma unroll
    for (int d = 32; d > 0; d >>= 1) s += __shfl_down(s, d);
    if (l == 0) out[0] = s * (1.0f / 128.0f);
}

extern "C" void kernel_launch(void* const* d_in, const int* in_sizes, int n_in,
                              void* d_out, int out_size, void* d_ws, size_t ws_size,
                              hipStream_t stream) {
    const float* emissions = (const float*)d_in[0];
    const int*   tags      = (const int*)  d_in[1];
    const float* mask      = (const float*)d_in[2];
    const float* trans     = (const float*)d_in[3];
    float* out = (float*)d_out;
    float* ws  = (float*)d_ws;           // 128 floats of scratch

    crf_main<<<dim3(128), dim3(256), 0, stream>>>(emissions, tags, mask, trans, ws);
    crf_finalize<<<dim3(1), dim3(64), 0, stream>>>(ws, out);
}

// Round 5
// 338.699 us; speedup vs baseline: 1.7711x; 1.7711x over previous
//
#include <hip/hip_runtime.h>

typedef short s8v __attribute__((ext_vector_type(8)));   // 8 bf16 (guide §3 frag_ab)
typedef float f4v __attribute__((ext_vector_type(4)));   // MFMA accumulator

#define LOG2E 1.4426950408889634f
#define LN2   0.6931471805599453f

__device__ __forceinline__ float fast_exp2(float x) {
#if __has_builtin(__builtin_amdgcn_exp2f)
    return __builtin_amdgcn_exp2f(x);
#else
    return exp2f(x);
#endif
}

// f32 -> bf16 (RNE). bf16 keeps the full f32 exponent range: no under/overflow.
__device__ __forceinline__ unsigned short f2bf(float x) {
    unsigned int u = __float_as_uint(x);
    return (unsigned short)((u + 0x7fffu + ((u >> 16) & 1u)) >> 16);
}

// One block per batch element b; thread j owns output column j (= 64*wave + lane).
// Exp-space linear recursion (R2-proven numerics), matvec done by MFMA:
//   A(16x32) = u chunk, all 16-lane row-groups hold the SAME u values -> all D rows = v.
//   B(32x16) = E slice, resident in VGPRs/AGPRs for the whole kernel.
// Per wave per step: 8 ds_read_b128 (u frags) + 32 MFMA. The matrix unit does the
// broadcast that cost R2 128 LDS reads and R4 the readlane hazard wall.
__launch_bounds__(256, 1)
__global__ void crf_main(const float* __restrict__ emissions,
                         const int*   __restrict__ tags,
                         const float* __restrict__ mask,
                         const float* __restrict__ trans,
                         float*       __restrict__ ws) {
    const int T = 512, N = 256;
    const int b  = blockIdx.x;
    const int j  = threadIdx.x;
    const int l  = j & 63;          // lane
    const int w  = j >> 6;          // wave
    const int lg = l >> 4;          // 16-lane group (K sub-chunk)
    const int ll = l & 15;          // position in group (N dim)

    __shared__ alignas(16) unsigned short u_lds[256];  // u as bf16, k-contiguous
    __shared__ float v0f;
    __shared__ float cm2_lds[256];
    __shared__ float red[256];

    // ---- per-column log2-max of trans (thread j -> column j, coalesced) ----
    const float* tcol = trans + j;
    float cmax = -1e30f;
    #pragma unroll 8
    for (int i = 0; i < N; ++i) cmax = fmaxf(cmax, tcol[i * N]);
    cm2_lds[j] = cmax * LOG2E;
    __syncthreads();
    const float cm2 = cm2_lds[j];   // own column's, kept in a register

    // ---- E fragments (B operand), registers for the whole kernel ----
    // tile c: cols 64w+16c+ll ; chunk q: k = 32q + 8*lg + e  (same kmap as u frags:
    // any HW k-permutation within (lg,e) slots cancels between A and B).
    s8v Efr[4][8];
    #pragma unroll
    for (int c = 0; c < 4; ++c) {
        const int   col = 64 * w + 16 * c + ll;
        const float cc  = cm2_lds[col];
        #pragma unroll
        for (int q = 0; q < 8; ++q) {
            s8v e;
            #pragma unroll
            for (int el = 0; el < 8; ++el) {
                const int k = 32 * q + 8 * lg + el;
                e[el] = (short)f2bf(fast_exp2(trans[k * N + col] * LOG2E - cc));
            }
            Efr[c][q] = e;
        }
    }

    // ---- init: v = 2^(log2e * emit[b,0,j]) ----
    const float* em_base = emissions + ((size_t)b * T) * N + j;
    float v = fast_exp2(em_base[0] * LOG2E);
    float C = 0.f;
    float em_next  = em_base[N];
    float em_next2 = em_base[2 * N];

    if (j == 0) v0f = v;
    __syncthreads();
    {
        int   e = (__float_as_int(v0f) >> 23) & 0xff;   // biased exponent of v0
        float r = __int_as_float((252 - e) << 23);      // exact 2^(-k-2)
        C += (float)(e - 125);                          // k + 2
        u_lds[j] = f2bf(v * r);
    }
    __syncthreads();

    for (int t = 1; t < T; ++t) {
        // u fragments: chunk q -> 16B at byte 64q + 16*lg (contiguous per lane-group,
        // 16-lane broadcast, distinct banks across groups: conflict-free)
        const uint4* ub = (const uint4*)u_lds;
        s8v ua[8];
        #pragma unroll
        for (int q = 0; q < 8; ++q)
            ua[q] = __builtin_bit_cast(s8v, ub[4 * q + lg]);

        f4v d0 = {0.f, 0.f, 0.f, 0.f}, d1 = d0, d2 = d0, d3 = d0;
        #pragma unroll
        for (int q = 0; q < 8; ++q) {
            d0 = __builtin_amdgcn_mfma_f32_16x16x32_bf16(ua[q], Efr[0][q], d0, 0, 0, 0);
            d1 = __builtin_amdgcn_mfma_f32_16x16x32_bf16(ua[q], Efr[1][q], d1, 0, 0, 0);
            d2 = __builtin_amdgcn_mfma_f32_16x16x32_bf16(ua[q], Efr[2][q], d2, 0, 0, 0);
            d3 = __builtin_amdgcn_mfma_f32_16x16x32_bf16(ua[q], Efr[3][q], d3, 0, 0, 0);
        }
        // all D rows equal; col = ll. Thread j's column j sits in tile lg. Static select.
        float vraw = (lg == 0) ? d0[0] : (lg == 1) ? d1[0] : (lg == 2) ? d2[0] : d3[0];

        float em = em_next;
        em_next = em_next2;
        if (t + 2 < T) em_next2 = em_base[(size_t)(t + 2) * N];

        v = vraw * fast_exp2(fmaf(em, LOG2E, cm2));     // fold emit + colmax back in

        if (j == 0) v0f = v;
        __syncthreads();                                 // bar A: v0 ready, u reads done
        if (t < T - 1) {
            int   e = (__float_as_int(v0f) >> 23) & 0xff;
            float r = __int_as_float((252 - e) << 23);   // 2^(-k-2), fresh k
            C += (float)(e - 125);
            u_lds[j] = f2bf(v * r);                      // bf16: no range hazard
        }
        __syncthreads();                                 // bar B: u ready
    }

    // ---- Z_b = ln2 * (C + log2(sum_j v_j)) ----
    red[j] = v;
    __syncthreads();
    #pragma unroll
    for (int s = 128; s > 0; s >>= 1) {
        if (j < s) red[j] += red[j + s];
        __syncthreads();
    }
    float Z = (C + log2f(red[0])) * LN2;
    __syncthreads();   // everyone done reading red[0] before reuse

    // ---- gold score (gather) ----
    float gp = 0.f;
    const int*   tg  = tags + (size_t)b * T;
    const float* mk  = mask + (size_t)b * T;
    const float* emb = emissions + ((size_t)b * T) * N;
    for (int t = 1 + j; t < T; t += 256) {
        int tt = tg[t], tp = tg[t - 1];
        gp += (emb[(size_t)t * N + tt] + trans[(size_t)tp * N + tt]) * mk[t];
    }
    if (j == 0) gp += emb[tg[0]];
    red[j] = gp;
    __syncthreads();
    #pragma unroll
    for (int s = 128; s > 0; s >>= 1) {
        if (j < s) red[j] += red[j + s];
        __syncthreads();
    }
    if (j == 0) ws[b] = Z - red[0];
}

// Deterministic mean over the 128 per-batch results.
__global__ void crf_finalize(const float* __restrict__ ws, float* __restrict__ out) {
    int l = threadIdx.x;                 // 64 threads, one wave
    float s = ws[l] + ws[l + 64];
    #pragma unroll
    for (int d = 32; d > 0; d >>= 1) s += __shfl_down(s, d);
    if (l == 0) out[0] = s * (1.0f / 128.0f);
}

extern "C" void kernel_launch(void* const* d_in, const int* in_sizes, int n_in,
                              void* d_out, int out_size, void* d_ws, size_t ws_size,
                              hipStream_t stream) {
    const float* emissions = (const float*)d_in[0];
    const int*   tags      = (const int*)  d_in[1];
    const float* mask      = (const float*)d_in[2];
    const float* trans     = (const float*)d_in[3];
    float* out = (float*)d_out;
    float* ws  = (float*)d_ws;           // 128 floats of scratch

    crf_main<<<dim3(128), dim3(256), 0, stream>>>(emissions, tags, mask, trans, ws);
    crf_finalize<<<dim3(1), dim3(64), 0, stream>>>(ws, out);
}

// Round 7
// 297.405 us; speedup vs baseline: 2.0170x; 1.1388x over previous
//
#include <hip/hip_runtime.h>

typedef short s8v __attribute__((ext_vector_type(8)));   // 8 bf16 (guide §3 frag_ab)
typedef float f4v __attribute__((ext_vector_type(4)));   // MFMA accumulator
typedef int   i4v __attribute__((ext_vector_type(4)));   // 16B int view for reg pin

#define LOG2E 1.4426950408889634f
#define LN2   0.6931471805599453f

// Raw barrier: LDS visibility only (lgkmcnt), vmcnt floats -> global prefetch stays async.
// Single asm so the compiler can neither split it nor move memory ops across it.
#define SYNC_LDS() __asm__ __volatile__("s_waitcnt lgkmcnt(0)\n\ts_barrier" ::: "memory")

__device__ __forceinline__ float fast_exp2(float x) {
#if __has_builtin(__builtin_amdgcn_exp2f)
    return __builtin_amdgcn_exp2f(x);
#else
    return exp2f(x);
#endif
}

// f32 -> bf16 (RNE). bf16 keeps the full f32 exponent range: no under/overflow.
__device__ __forceinline__ unsigned short f2bf(float x) {
    unsigned int u = __float_as_uint(x);
    return (unsigned short)((u + 0x7fffu + ((u >> 16) & 1u)) >> 16);
}

// One block per batch element b; thread j owns output column j (= 64*wave + lane).
// Exp-space linear recursion, matvec on MFMA (R5-proven engine):
//   A(16x32) = u chunk, all 16-lane row-groups hold the SAME u values -> all D rows = v.
//   B(32x16) = E slice, VGPR-resident for the whole kernel.
// ONE raw barrier per step: u renormalized by the exponent of the PREVIOUS stored
// u(0) (read for free from the u vector itself) -> memoryless, stable, exact pow2.
__launch_bounds__(256, 1)
__global__ void crf_main(const float* __restrict__ emissions,
                         const int*   __restrict__ tags,
                         const float* __restrict__ mask,
                         const float* __restrict__ trans,
                         float*       __restrict__ ws) {
    const int T = 512, N = 256;
    const int b  = blockIdx.x;
    const int j  = threadIdx.x;
    const int l  = j & 63;          // lane
    const int w  = j >> 6;          // wave
    const int lg = l >> 4;          // 16-lane group (K sub-chunk)
    const int ll = l & 15;          // position in group (N dim)

    __shared__ alignas(16) unsigned short u_lds[2][256];  // u as bf16, double-buffered
    __shared__ float cm2_lds[256];
    __shared__ float red[256];

    // ---- per-column log2-max of trans (thread j -> column j, coalesced) ----
    const float* tcol = trans + j;
    float cmax = -1e30f;
    #pragma unroll 8
    for (int i = 0; i < N; ++i) cmax = fmaxf(cmax, tcol[i * N]);
    cm2_lds[j] = cmax * LOG2E;
    __syncthreads();
    const float cm2 = cm2_lds[j];   // own column's, kept in a register

    // ---- E fragments (B operand), registers for the whole kernel ----
    // tile c: cols 64w+16c+ll ; chunk q: k = 32q + 8*lg + e  (same kmap as u frags:
    // any HW k-permutation within (lg,e) slots cancels between A and B).
    s8v Efr[4][8];
    #pragma unroll
    for (int c = 0; c < 4; ++c) {
        const int   col = 64 * w + 16 * c + ll;
        const float cc  = cm2_lds[col];
        #pragma unroll
        for (int q = 0; q < 8; ++q) {
            s8v e;
            #pragma unroll
            for (int el = 0; el < 8; ++el) {
                const int k = 32 * q + 8 * lg + el;
                e[el] = (short)f2bf(fast_exp2(trans[k * N + col] * LOG2E - cc));
            }
            i4v ei = __builtin_bit_cast(i4v, e);       // keep compiler honest about
            asm volatile("" : "+v"(ei));               // VGPR residency
            Efr[c][q] = __builtin_bit_cast(s8v, ei);
        }
    }

    // ---- init: u_0 = bf16(2^(log2e * emit[b,0,j])), C = 0 ----
    const float* em_base = emissions + ((size_t)b * T) * N + j;
    float v = fast_exp2(em_base[0] * LOG2E);           // |log2 v| <= ~10: fits bf16
    float C = 0.f;
    float em_next  = em_base[N];
    float em_next2 = em_base[2 * N];
    u_lds[0][j] = f2bf(v);
    SYNC_LDS();

    for (int t = 1; t < T; ++t) {
        const int pb = (t - 1) & 1;
        // u fragments: chunk q -> 16B at byte 64q + 16*lg (16-lane broadcast groups,
        // distinct banks across groups: conflict-free) + u(0) broadcast (free)
        const uint4* ub = (const uint4*)u_lds[pb];
        s8v ua[8];
        #pragma unroll
        for (int q = 0; q < 8; ++q)
            ua[q] = __builtin_bit_cast(s8v, ub[4 * q + lg]);
        const unsigned int u0b = u_lds[pb][0];         // exponent reference, same-addr read

        float em = em_next;
        em_next = em_next2;
        if (t + 2 < T) em_next2 = em_base[(size_t)(t + 2) * N];  // vmcnt never drained

        f4v d0 = {0.f, 0.f, 0.f, 0.f}, d1 = d0, d2 = d0, d3 = d0;
        #pragma unroll
        for (int q = 0; q < 8; ++q) {
            d0 = __builtin_amdgcn_mfma_f32_16x16x32_bf16(ua[q], Efr[0][q], d0, 0, 0, 0);
            d1 = __builtin_amdgcn_mfma_f32_16x16x32_bf16(ua[q], Efr[1][q], d1, 0, 0, 0);
            d2 = __builtin_amdgcn_mfma_f32_16x16x32_bf16(ua[q], Efr[2][q], d2, 0, 0, 0);
            d3 = __builtin_amdgcn_mfma_f32_16x16x32_bf16(ua[q], Efr[3][q], d3, 0, 0, 0);
        }
        // all D rows equal; thread j's column sits in tile lg, slot ll. Static select.
        float vraw = (lg == 0) ? d0[0] : (lg == 1) ? d1[0] : (lg == 2) ? d2[0] : d3[0];
        v = vraw * fast_exp2(fmaf(em, LOG2E, cm2));    // fold emit + colmax back in

        if (t < T - 1) {
            // k = ilogb(u_prev(0)) + 4 : uniform across threads, memoryless (stable),
            // exact power-of-two scale -> C accounting exact.
            int e = (int)((u0b >> 7) & 0xffu);          // biased bf16 exponent
            float r = __int_as_float((250 - e) << 23);  // 2^-(e-127+4)
            C += (float)(e - 123);
            u_lds[t & 1][j] = f2bf(v * r);
        }
        SYNC_LDS();
    }

    // ---- Z_b = ln2 * (C + log2(sum_j v_j)), v in scale 2^-C ----
    red[j] = v;
    __syncthreads();
    #pragma unroll
    for (int s = 128; s > 0; s >>= 1) {
        if (j < s) red[j] += red[j + s];
        __syncthreads();
    }
    float Z = (C + log2f(red[0])) * LN2;
    __syncthreads();   // everyone done reading red[0] before reuse

    // ---- gold score (gather) ----
    float gp = 0.f;
    const int*   tg  = tags + (size_t)b * T;
    const float* mk  = mask + (size_t)b * T;
    const float* emb = emissions + ((size_t)b * T) * N;
    for (int t = 1 + j; t < T; t += 256) {
        int tt = tg[t], tp = tg[t - 1];
        gp += (emb[(size_t)t * N + tt] + trans[(size_t)tp * N + tt]) * mk[t];
    }
    if (j == 0) gp += emb[tg[0]];
    red[j] = gp;
    __syncthreads();
    #pragma unroll
    for (int s = 128; s > 0; s >>= 1) {
        if (j < s) red[j] += red[j + s];
        __syncthreads();
    }
    if (j == 0) ws[b] = Z - red[0];
}

// Deterministic mean over the 128 per-batch results.
__global__ void crf_finalize(const float* __restrict__ ws, float* __restrict__ out) {
    int l = threadIdx.x;                 // 64 threads, one wave
    float s = ws[l] + ws[l + 64];
    #pragma unroll
    for (int d = 32; d > 0; d >>= 1) s += __shfl_down(s, d);
    if (l == 0) out[0] = s * (1.0f / 128.0f);
}

extern "C" void kernel_launch(void* const* d_in, const int* in_sizes, int n_in,
                              void* d_out, int out_size, void* d_ws, size_t ws_size,
                              hipStream_t stream) {
    const float* emissions = (const float*)d_in[0];
    const int*   tags      = (const int*)  d_in[1];
    const float* mask      = (const float*)d_in[2];
    const float* trans     = (const float*)d_in[3];
    float* out = (float*)d_out;
    float* ws  = (float*)d_ws;           // 128 floats of scratch

    crf_main<<<dim3(128), dim3(256), 0, stream>>>(emissions, tags, mask, trans, ws);
    crf_finalize<<<dim3(1), dim3(64), 0, stream>>>(ws, out);
}